// Round 1
// baseline (292.693 us; speedup 1.0000x reference)
//
#include <hip/hip_runtime.h>
#include <stdint.h>

// ---------------- problem constants ----------------
#define B_SZ 8192
#define E_SZ 8
#define H_SZ 128
#define LOG8 2.0794415416798357f   // -log(1/8)

typedef __attribute__((ext_vector_type(8))) short short8;
typedef __attribute__((ext_vector_type(4))) float floatx4;

__device__ inline unsigned short f2bf(float f) {
    unsigned int u = __float_as_uint(f);
    u = (u + 0x7FFFu + ((u >> 16) & 1u)) >> 16;   // RNE
    return (unsigned short)u;
}
__device__ inline float bf2f(unsigned short s) {
    return __uint_as_float(((unsigned int)s) << 16);
}
__device__ inline float wredf(float x) {
#pragma unroll
    for (int o = 32; o; o >>= 1) x += __shfl_down(x, o);
    return x;
}
__device__ inline int wredi(int x) {
#pragma unroll
    for (int o = 32; o; o >>= 1) x += __shfl_down(x, o);
    return x;
}

// ---------------- prep: normalize embeddings -> bf16 ----------------
// one wave per row; lane i handles cols 2i,2i+1
__global__ void prep_embed(const float* __restrict__ emb,
                           unsigned short* __restrict__ nrm) {
    int wave = threadIdx.x >> 6, lane = threadIdx.x & 63;
    int row = (blockIdx.x << 2) + wave;
    const float2* e2 = (const float2*)(emb + (size_t)row * H_SZ);
    float2 v = e2[lane];
    float ss = v.x * v.x + v.y * v.y;
    ss = wredf(ss);
    ss = __shfl(ss, 0);
    float inv = rsqrtf(ss);
    ushort2 o;
    o.x = f2bf(v.x * inv);
    o.y = f2bf(v.y * inv);
    ((ushort2*)(nrm + (size_t)row * H_SZ))[lane] = o;
}

// ---------------- prep: per-row routing/softmax/CE + cheap reductions ----------------
// acc layout (floats): [0]=task_sum [1]=eff_sum [2]=ent_sum [3]=kl_sum
//                      [4..11]=col_sums, uint at [12] = pair count
__global__ void prep_row(const float* __restrict__ logits,
                         const int* __restrict__ targets,
                         const float* __restrict__ routing,
                         unsigned short* __restrict__ lq,   // bf16(logp - log(1/8))
                         unsigned short* __restrict__ pb,   // bf16(softmax)
                         float* __restrict__ aprime,        // sum p~ * lq~ (fp32)
                         float* __restrict__ acc) {
    int row = blockIdx.x * 256 + threadIdx.x;
    int lane = threadIdx.x & 63;

    const float4* r4 = (const float4*)(routing + (size_t)row * E_SZ);
    float4 va = r4[0], vb = r4[1];
    float v[8] = {va.x, va.y, va.z, va.w, vb.x, vb.y, vb.z, vb.w};

    // softmax over the routing values themselves (per reference)
    float mx = v[0];
#pragma unroll
    for (int e = 1; e < 8; ++e) mx = fmaxf(mx, v[e]);
    float ex[8], s = 0.f;
#pragma unroll
    for (int e = 0; e < 8; ++e) { ex[e] = expf(v[e] - mx); s += ex[e]; }
    float ls = logf(s);
    float inv_s = 1.f / s;

    union { unsigned short u[8]; uint4 q; } lu, pu;
    float ap = 0.f;
#pragma unroll
    for (int e = 0; e < 8; ++e) {
        unsigned short pe = f2bf(ex[e] * inv_s);
        unsigned short le = f2bf(v[e] - mx - ls + LOG8);
        pu.u[e] = pe;
        lu.u[e] = le;
        ap += bf2f(pe) * bf2f(le);   // a'[row] consistent with bf16 operands
    }
    ((uint4*)lq)[row] = lu.q;
    ((uint4*)pb)[row] = pu.q;
    aprime[row] = ap;

    // efficiency + entropy terms use RAW routing values
    float eff = 0.f, ent = 0.f;
#pragma unroll
    for (int e = 0; e < 8; ++e) {
        if (v[e] < 0.1f) eff += v[e];
        ent += v[e] * logf(v[e] + 1e-8f);
    }

    // task CE over 3 classes
    const float* lg = logits + (size_t)row * 3;
    float a0 = lg[0], a1 = lg[1], a2 = lg[2];
    float mm = fmaxf(a0, fmaxf(a1, a2));
    float lse = mm + logf(expf(a0 - mm) + expf(a1 - mm) + expf(a2 - mm));
    int tg = targets[row];
    float tv = (tg == 0) ? a0 : ((tg == 1) ? a1 : a2);
    float task = lse - tv;

    task = wredf(task);
    eff = wredf(eff);
    ent = wredf(ent);
    float cs[8];
#pragma unroll
    for (int e = 0; e < 8; ++e) cs[e] = wredf(v[e]);

    if (lane == 0) {
        atomicAdd(&acc[0], task);
        atomicAdd(&acc[1], eff);
        atomicAdd(&acc[2], ent);
#pragma unroll
        for (int e = 0; e < 8; ++e) atomicAdd(&acc[4 + e], cs[e]);
    }
}

// ---------------- main: fused sim-mask + KL accumulation ----------------
// block tile: 128 rows (i) x 64 cols (j); 4 waves in 2x2, each 64x32 (4x2 C-tiles)
__global__ __launch_bounds__(256, 2) void tile_kl(
    const unsigned short* __restrict__ nrm,
    const unsigned short* __restrict__ lq,
    const unsigned short* __restrict__ pb,
    const float* __restrict__ aprime,
    float* __restrict__ acc) {
    __shared__ unsigned short Ash[128][136];   // +8 pad: 2-way bank alias (free)
    __shared__ unsigned short Bsh[64][136];
    __shared__ unsigned short lqsh[128][8];
    __shared__ unsigned short psh[64][8];
    __shared__ float ash[64];
    __shared__ float redk[4];
    __shared__ int redc[4];

    const int t = threadIdx.x;
    const int iBase = blockIdx.y << 7;   // 64 row-tiles
    const int jBase = blockIdx.x << 6;   // 128 col-tiles

    // stage A (128x128 bf16) and B (64x128 bf16) as 16B chunks
    const uint4* n4 = (const uint4*)nrm;   // 16 uint4 per row
#pragma unroll
    for (int it = 0; it < 8; ++it) {
        int c = t + (it << 8);            // 0..2047
        int row = c >> 4, cc = c & 15;
        *(uint4*)&Ash[row][cc << 3] = n4[((size_t)(iBase + row) << 4) + cc];
    }
#pragma unroll
    for (int it = 0; it < 4; ++it) {
        int c = t + (it << 8);            // 0..1023
        int row = c >> 4, cc = c & 15;
        *(uint4*)&Bsh[row][cc << 3] = n4[((size_t)(jBase + row) << 4) + cc];
    }
    if (t < 128) {
        *(uint4*)&lqsh[t][0] = ((const uint4*)lq)[iBase + t];
    } else if (t < 192) {
        int r = t - 128;
        *(uint4*)&psh[r][0] = ((const uint4*)pb)[jBase + r];
    } else {
        int r = t - 192;
        ash[r] = aprime[jBase + r];
    }
    __syncthreads();

    const int wave = t >> 6, lane = t & 63;
    const int wr = wave >> 1, wc = wave & 1;
    const int m = lane & 15, q = lane >> 4;

    floatx4 simacc[4][2];
#pragma unroll
    for (int a = 0; a < 4; ++a)
#pragma unroll
        for (int b = 0; b < 2; ++b) simacc[a][b] = (floatx4){0.f, 0.f, 0.f, 0.f};

    // sim = A . B^T over K=128 (4 k-steps of 32)
#pragma unroll
    for (int ks = 0; ks < 4; ++ks) {
        const int k0 = (ks << 5) + (q << 3);
        short8 af[4], bf_[2];
#pragma unroll
        for (int a = 0; a < 4; ++a)
            af[a] = *(const short8*)&Ash[(wr << 6) + (a << 4) + m][k0];
#pragma unroll
        for (int b = 0; b < 2; ++b)
            bf_[b] = *(const short8*)&Bsh[(wc << 5) + (b << 4) + m][k0];
#pragma unroll
        for (int a = 0; a < 4; ++a)
#pragma unroll
            for (int b = 0; b < 2; ++b)
                simacc[a][b] = __builtin_amdgcn_mfma_f32_16x16x32_bf16(
                    af[a], bf_[b], simacc[a][b], 0, 0, 0);
    }

    // cross term lq_i . p_j via one zero-padded K=8 MFMA per C-tile
    const short8 zero8 = (short8){0, 0, 0, 0, 0, 0, 0, 0};
    short8 lqf[4], pf[2];
#pragma unroll
    for (int a = 0; a < 4; ++a)
        lqf[a] = (q == 0) ? *(const short8*)&lqsh[(wr << 6) + (a << 4) + m][0] : zero8;
#pragma unroll
    for (int b = 0; b < 2; ++b)
        pf[b] = (q == 0) ? *(const short8*)&psh[(wc << 5) + (b << 4) + m][0] : zero8;

    float klLocal = 0.f;
    int cntLocal = 0;
#pragma unroll
    for (int a = 0; a < 4; ++a) {
        const int gRow0 = iBase + (wr << 6) + (a << 4) + (q << 2);  // + r
#pragma unroll
        for (int b = 0; b < 2; ++b) {
            const int gCol = jBase + (wc << 5) + (b << 4) + m;
            const float ap = ash[(wc << 5) + (b << 4) + m];
            floatx4 cr = __builtin_amdgcn_mfma_f32_16x16x32_bf16(
                lqf[a], pf[b], (floatx4){0.f, 0.f, 0.f, 0.f}, 0, 0, 0);
#pragma unroll
            for (int r = 0; r < 4; ++r) {
                bool ok = (simacc[a][b][r] > 0.8f) && (gRow0 + r != gCol);
                if (ok) {
                    klLocal += ap - cr[r];
                    cntLocal += 1;
                }
            }
        }
    }

    klLocal = wredf(klLocal);
    cntLocal = wredi(cntLocal);
    if (lane == 0) { redk[wave] = klLocal; redc[wave] = cntLocal; }
    __syncthreads();
    if (t == 0) {
        atomicAdd(&acc[3], redk[0] + redk[1] + redk[2] + redk[3]);
        atomicAdd((unsigned int*)&acc[12],
                  (unsigned int)(redc[0] + redc[1] + redc[2] + redc[3]));
    }
}

// ---------------- finalize ----------------
__global__ void finalize_k(const float* __restrict__ acc,
                           const float* __restrict__ temp,
                           float* __restrict__ out) {
    const float invB = 1.f / (float)B_SZ;
    float task = acc[0] * invB;
    float eff = 0.05f * acc[1] * invB;
    float entl = 0.01f * acc[2] * invB;   // acc[2] = sum v*log(v+eps) = -sum(entropy)
    unsigned int cnt = ((const unsigned int*)acc)[12];
    float cons = 0.1f * (cnt > 0 ? acc[3] / (float)cnt : 0.f);
    float u[8], mean = 0.f;
    for (int e = 0; e < 8; ++e) { u[e] = acc[4 + e] * invB; mean += u[e]; }
    mean *= 0.125f;
    float var = 0.f;
    for (int e = 0; e < 8; ++e) { float d = u[e] - mean; var += d * d; }
    var *= (1.f / 7.f);                    // unbiased (ddof=1)
    float lb = 0.1f * var * 64.f;          // * E^2
    float tt = temp[0] - 1.f;
    out[0] = task + lb + eff + cons + entl + 0.01f * tt * tt;
}

// ---------------- launch ----------------
extern "C" void kernel_launch(void* const* d_in, const int* in_sizes, int n_in,
                              void* d_out, int out_size, void* d_ws, size_t ws_size,
                              hipStream_t stream) {
    const float* logits = (const float*)d_in[0];
    const int* targets = (const int*)d_in[1];
    const float* routing = (const float*)d_in[2];
    const float* emb = (const float*)d_in[3];
    const float* temp = (const float*)d_in[4];

    char* ws = (char*)d_ws;
    unsigned short* nrm = (unsigned short*)ws;               // 8192*128*2 = 2097152
    unsigned short* lq = (unsigned short*)(ws + 2097152);    // 8192*8*2  = 131072
    unsigned short* pb = (unsigned short*)(ws + 2228224);    // 131072
    float* aprime = (float*)(ws + 2359296);                  // 32768
    float* acc = (float*)(ws + 2392064);                     // 64 bytes

    hipMemsetAsync(acc, 0, 64, stream);
    prep_embed<<<B_SZ / 4, 256, 0, stream>>>(emb, nrm);
    prep_row<<<B_SZ / 256, 256, 0, stream>>>(logits, targets, routing, lq, pb, aprime, acc);
    tile_kl<<<dim3(128, 64), 256, 0, stream>>>(nrm, lq, pb, aprime, acc);
    finalize_k<<<1, 1, 0, stream>>>(acc, temp, (float*)d_out);
}

// Round 2
// 124.465 us; speedup vs baseline: 2.3516x; 2.3516x over previous
//
#include <hip/hip_runtime.h>
#include <stdint.h>

// ---------------- problem constants ----------------
#define B_SZ 8192
#define LOG8 2.0794415416798357f   // -log(1/8)

typedef __attribute__((ext_vector_type(8))) short short8;
typedef __attribute__((ext_vector_type(4))) float floatx4;

__device__ inline unsigned short f2bf(float f) {
    unsigned int u = __float_as_uint(f);
    u = (u + 0x7FFFu + ((u >> 16) & 1u)) >> 16;   // RNE
    return (unsigned short)u;
}
__device__ inline float bf2f(unsigned short s) {
    return __uint_as_float(((unsigned int)s) << 16);
}
__device__ inline float wredf(float x) {
#pragma unroll
    for (int o = 32; o; o >>= 1) x += __shfl_down(x, o);
    return x;
}
__device__ inline int wredi(int x) {
#pragma unroll
    for (int o = 32; o; o >>= 1) x += __shfl_down(x, o);
    return x;
}

// ---------------- fused prep: embeddings + per-row routing/CE ----------------
// blocks 0..2047: normalize 4 embedding rows each (wave per row)
// blocks 2048..2079: routing softmax / CE / cheap reductions, 256 rows each
// acc layout: f32[0]=task [1]=eff [2]=ent [4..11]=col_sums
//             f32[16..79]=kl partial slots, u32[80..143]=cnt partial slots
__global__ void prep_all(const float* __restrict__ logits,
                         const int* __restrict__ targets,
                         const float* __restrict__ routing,
                         const float* __restrict__ emb,
                         unsigned short* __restrict__ nrm,
                         unsigned short* __restrict__ lq,
                         unsigned short* __restrict__ pb,
                         float* __restrict__ aprime,
                         float* __restrict__ acc) {
    const int bid = blockIdx.x;
    const int lane = threadIdx.x & 63;

    if (bid < 2048) {
        // ---- embedding normalize -> bf16 ----
        int wave = threadIdx.x >> 6;
        int row = (bid << 2) + wave;
        const float2* e2 = (const float2*)(emb + (size_t)row * 128);
        float2 v = e2[lane];
        float ss = v.x * v.x + v.y * v.y;
        ss = wredf(ss);
        ss = __shfl(ss, 0);
        float inv = rsqrtf(ss);
        ushort2 o;
        o.x = f2bf(v.x * inv);
        o.y = f2bf(v.y * inv);
        ((ushort2*)(nrm + (size_t)row * 128))[lane] = o;
        return;
    }

    // ---- per-row routing prep ----
    int row = ((bid - 2048) << 8) + threadIdx.x;

    const float4* r4 = (const float4*)(routing + (size_t)row * 8);
    float4 va = r4[0], vb = r4[1];
    float v[8] = {va.x, va.y, va.z, va.w, vb.x, vb.y, vb.z, vb.w};

    float mx = v[0];
#pragma unroll
    for (int e = 1; e < 8; ++e) mx = fmaxf(mx, v[e]);
    float ex[8], s = 0.f;
#pragma unroll
    for (int e = 0; e < 8; ++e) { ex[e] = expf(v[e] - mx); s += ex[e]; }
    float ls = logf(s);
    float inv_s = 1.f / s;

    union { unsigned short u[8]; uint4 q; } lu, pu;
    float ap = 0.f;
#pragma unroll
    for (int e = 0; e < 8; ++e) {
        unsigned short pe = f2bf(ex[e] * inv_s);
        unsigned short le = f2bf(v[e] - mx - ls + LOG8);
        pu.u[e] = pe;
        lu.u[e] = le;
        ap += bf2f(pe) * bf2f(le);
    }
    ((uint4*)lq)[row] = lu.q;
    ((uint4*)pb)[row] = pu.q;
    aprime[row] = ap;

    float eff = 0.f, ent = 0.f;
#pragma unroll
    for (int e = 0; e < 8; ++e) {
        if (v[e] < 0.1f) eff += v[e];
        ent += v[e] * logf(v[e] + 1e-8f);
    }

    const float* lg = logits + (size_t)row * 3;
    float a0 = lg[0], a1 = lg[1], a2 = lg[2];
    float mm = fmaxf(a0, fmaxf(a1, a2));
    float lse = mm + logf(expf(a0 - mm) + expf(a1 - mm) + expf(a2 - mm));
    int tg = targets[row];
    float tv = (tg == 0) ? a0 : ((tg == 1) ? a1 : a2);
    float task = lse - tv;

    task = wredf(task);
    eff = wredf(eff);
    ent = wredf(ent);
    float cs[8];
#pragma unroll
    for (int e = 0; e < 8; ++e) cs[e] = wredf(v[e]);

    if (lane == 0) {
        atomicAdd(&acc[0], task);
        atomicAdd(&acc[1], eff);
        atomicAdd(&acc[2], ent);
#pragma unroll
        for (int e = 0; e < 8; ++e) atomicAdd(&acc[4 + e], cs[e]);
    }
}

// ---------------- main: fused sim-mask + KL accumulation ----------------
// 128x128 tile, 512 threads (8 waves in 2x4), XOR-swizzled LDS (64 KB, no pad)
__global__ __launch_bounds__(512, 4) void tile_kl(
    const unsigned short* __restrict__ nrm,
    const unsigned short* __restrict__ lq,
    const unsigned short* __restrict__ pb,
    const float* __restrict__ aprime,
    float* __restrict__ acc) {
    __shared__ uint4 sh[2][128][16];   // [0]=A rows, [1]=B rows; exactly 64 KB

    const int t = threadIdx.x;
    const int iBase = blockIdx.y << 7;
    const int jBase = blockIdx.x << 7;

    // stage: 16B granule g of row r stored at physical column g ^ (r & 15)
    const uint4* n4 = (const uint4*)nrm;   // 16 granules per 128-elem row
#pragma unroll
    for (int it = 0; it < 4; ++it) {
        int c = t + (it << 9);            // 0..2047
        int row = c >> 4, g = c & 15;
        int gp = g ^ (row & 15);
        sh[0][row][gp] = n4[((size_t)(iBase + row) << 4) + g];
        sh[1][row][gp] = n4[((size_t)(jBase + row) << 4) + g];
    }

    const int wave = t >> 6, lane = t & 63;
    const int wr = wave >> 2, wc = wave & 3;   // 2 x 4 wave grid
    const int m = lane & 15, q = lane >> 4;

    // cross-term fragments straight from global (L2-hot, tiny)
    const short8 zero8 = (short8){0, 0, 0, 0, 0, 0, 0, 0};
    short8 lqf[4], pf[2];
    float ap[2];
#pragma unroll
    for (int a = 0; a < 4; ++a) {
        int r = iBase + (wr << 6) + (a << 4) + m;
        lqf[a] = (q == 0) ? *(const short8*)&lq[(size_t)r << 3] : zero8;
    }
#pragma unroll
    for (int b = 0; b < 2; ++b) {
        int cj = jBase + (wc << 5) + (b << 4) + m;
        pf[b] = (q == 0) ? *(const short8*)&pb[(size_t)cj << 3] : zero8;
        ap[b] = aprime[cj];
    }

    __syncthreads();

    const unsigned short* Ab = (const unsigned short*)&sh[0][0][0];
    const unsigned short* Bb = (const unsigned short*)&sh[1][0][0];

    floatx4 simacc[4][2];
#pragma unroll
    for (int a = 0; a < 4; ++a)
#pragma unroll
        for (int b = 0; b < 2; ++b) simacc[a][b] = (floatx4){0.f, 0.f, 0.f, 0.f};

    // sim = A . B^T over K=128 (4 k-steps of 32)
#pragma unroll
    for (int ks = 0; ks < 4; ++ks) {
        const int g = (ks << 2) + q;      // granule index 0..15
        short8 af[4], bfr[2];
#pragma unroll
        for (int a = 0; a < 4; ++a) {
            int ra = (wr << 6) + (a << 4) + m;       // ra & 15 == m
            af[a] = *(const short8*)&Ab[(ra << 7) + ((g ^ m) << 3)];
        }
#pragma unroll
        for (int b = 0; b < 2; ++b) {
            int rb = (wc << 5) + (b << 4) + m;       // rb & 15 == m
            bfr[b] = *(const short8*)&Bb[(rb << 7) + ((g ^ m) << 3)];
        }
#pragma unroll
        for (int a = 0; a < 4; ++a)
#pragma unroll
            for (int b = 0; b < 2; ++b)
                simacc[a][b] = __builtin_amdgcn_mfma_f32_16x16x32_bf16(
                    af[a], bfr[b], simacc[a][b], 0, 0, 0);
    }

    // epilogue: mask + KL accumulate
    float klLocal = 0.f;
    int cntLocal = 0;
#pragma unroll
    for (int a = 0; a < 4; ++a) {
        const int gRow0 = iBase + (wr << 6) + (a << 4) + (q << 2);  // + r
#pragma unroll
        for (int b = 0; b < 2; ++b) {
            const int gCol = jBase + (wc << 5) + (b << 4) + m;
            floatx4 cr = __builtin_amdgcn_mfma_f32_16x16x32_bf16(
                lqf[a], pf[b], (floatx4){0.f, 0.f, 0.f, 0.f}, 0, 0, 0);
#pragma unroll
            for (int r = 0; r < 4; ++r) {
                if ((simacc[a][b][r] > 0.8f) && (gRow0 + r != gCol)) {
                    klLocal += ap[b] - cr[r];
                    cntLocal += 1;
                }
            }
        }
    }

    klLocal = wredf(klLocal);
    cntLocal = wredi(cntLocal);

    __syncthreads();                       // all LDS reads complete
    float* redk = (float*)&sh[0][0][0];    // reuse LDS for reduction
    int* redc = (int*)(redk + 8);
    if (lane == 0) { redk[wave] = klLocal; redc[wave] = cntLocal; }
    __syncthreads();
    if (t == 0) {
        float k = 0.f;
        int c = 0;
#pragma unroll
        for (int w = 0; w < 8; ++w) { k += redk[w]; c += redc[w]; }
        int slot = (blockIdx.y * 64 + blockIdx.x) & 63;
        atomicAdd(&acc[16 + slot], k);
        atomicAdd((unsigned int*)&((unsigned int*)acc)[80 + slot],
                  (unsigned int)c);
    }
}

// ---------------- finalize (1 block x 64) ----------------
__global__ void finalize_k(const float* __restrict__ acc,
                           const float* __restrict__ temp,
                           float* __restrict__ out) {
    int lane = threadIdx.x;
    float k = acc[16 + lane];
    int c = (int)((const unsigned int*)acc)[80 + lane];
    k = wredf(k);
    c = wredi(c);
    if (lane == 0) {
        const float invB = 1.f / (float)B_SZ;
        float task = acc[0] * invB;
        float eff = 0.05f * acc[1] * invB;
        float entl = 0.01f * acc[2] * invB;
        float cons = 0.1f * (c > 0 ? k / (float)c : 0.f);
        float u[8], mean = 0.f;
        for (int e = 0; e < 8; ++e) { u[e] = acc[4 + e] * invB; mean += u[e]; }
        mean *= 0.125f;
        float var = 0.f;
        for (int e = 0; e < 8; ++e) { float d = u[e] - mean; var += d * d; }
        var *= (1.f / 7.f);                // unbiased (ddof=1)
        float lb = 0.1f * var * 64.f;      // * E^2
        float tt = temp[0] - 1.f;
        out[0] = task + lb + eff + cons + entl + 0.01f * tt * tt;
    }
}

// ---------------- launch ----------------
extern "C" void kernel_launch(void* const* d_in, const int* in_sizes, int n_in,
                              void* d_out, int out_size, void* d_ws, size_t ws_size,
                              hipStream_t stream) {
    const float* logits = (const float*)d_in[0];
    const int* targets = (const int*)d_in[1];
    const float* routing = (const float*)d_in[2];
    const float* emb = (const float*)d_in[3];
    const float* temp = (const float*)d_in[4];

    char* ws = (char*)d_ws;
    unsigned short* nrm = (unsigned short*)ws;               // 8192*128*2 = 2097152
    unsigned short* lq = (unsigned short*)(ws + 2097152);    // 131072
    unsigned short* pb = (unsigned short*)(ws + 2228224);    // 131072
    float* aprime = (float*)(ws + 2359296);                  // 32768
    float* acc = (float*)(ws + 2392064);                     // 1024 bytes

    hipMemsetAsync(acc, 0, 1024, stream);
    prep_all<<<2080, 256, 0, stream>>>(logits, targets, routing, emb,
                                       nrm, lq, pb, aprime, acc);
    tile_kl<<<dim3(64, 64), 512, 0, stream>>>(nrm, lq, pb, aprime, acc);
    finalize_k<<<1, 64, 0, stream>>>(acc, temp, (float*)d_out);
}